// Round 5
// baseline (257.330 us; speedup 1.0000x reference)
//
#include <hip/hip_runtime.h>

// QuantFinanceAttention: B=2, T=2048, C=1024, H=16, dk=64. fp32 I/O, bf16 MFMA internals.
// cvt(all) | QKV gemm (rope fused) | flash (constant-max softmax, 2-wave blocks) | proj (64x128).

typedef __bf16 bf16x8 __attribute__((ext_vector_type(8)));
typedef float f32x4 __attribute__((ext_vector_type(4)));
typedef unsigned short u16x8 __attribute__((ext_vector_type(8)));

__device__ __forceinline__ unsigned short f2bf(float f) {
    union { float f; unsigned int u; } c; c.f = f;
    unsigned int u = c.u;
    unsigned int r = u + 0x7fffu + ((u >> 16) & 1u);  // RNE
    return (unsigned short)(r >> 16);
}
__device__ __forceinline__ void stage8_f32(unsigned short* dst, const float* src) {
    const float4 a = *(const float4*)src;
    const float4 b = *(const float4*)(src + 4);
    u16x8 v;
    v[0] = f2bf(a.x); v[1] = f2bf(a.y); v[2] = f2bf(a.z); v[3] = f2bf(a.w);
    v[4] = f2bf(b.x); v[5] = f2bf(b.y); v[6] = f2bf(b.z); v[7] = f2bf(b.w);
    *(u16x8*)dst = v;
}
__device__ __forceinline__ void async16(const unsigned short* g, unsigned short* l) {
    __builtin_amdgcn_global_load_lds(
        (const __attribute__((address_space(1))) void*)g,
        (__attribute__((address_space(3))) void*)l, 16, 0, 0);
}

// Fused fp32->bf16 convert. dst layout: [x(524288 g8) if hasX][Wq][Wk][Wv][Wo] (131072 g8 each).
__global__ __launch_bounds__(256) void cvt_all(
    const float* __restrict__ x, const float* __restrict__ Wq, const float* __restrict__ Wk,
    const float* __restrict__ Wv, const float* __restrict__ Wo,
    unsigned short* __restrict__ dst, int hasX, int n8)
{
    const int i = blockIdx.x * 256 + threadIdx.x;
    if (i >= n8) return;
    int r = i;
    const float* src; int off;
    const int xg = hasX ? 524288 : 0;
    if (r < xg) { src = x; off = r; }
    else {
        r -= xg;
        const int w = r >> 17, o = r & 131071;
        src = (w == 0) ? Wq : (w == 1) ? Wk : (w == 2) ? Wv : Wo;
        off = o;
    }
    stage8_f32(&dst[(size_t)i * 8], &src[(size_t)off * 8]);
}

// QKV: C[m,n] = sum_k A[m,k]*W[n,k], K=1024, 128x128 tile. W bf16 at base + z*1M.
// out = qkv bf16 head-major [z][bh][t][d], rope fused for z<2. A bf16 if A_BF16 else fp32.
template<int A_BF16>
__global__ __launch_bounds__(256) void gemm_qkv(
    const void* __restrict__ Av, const unsigned short* __restrict__ Wb,
    unsigned short* __restrict__ outv)
{
    constexpr int K = 1024, BK = 32;
    __shared__ __align__(16) unsigned short As[128 * BK];
    __shared__ __align__(16) unsigned short Bs[128 * BK];
    const int tid = threadIdx.x;
    const int wid = tid >> 6, lane = tid & 63, g = lane >> 4, l = lane & 15;
    const int wm = (wid & 1) * 64, wn = (wid >> 1) * 64;
    const int m0 = blockIdx.y * 128, n0 = blockIdx.x * 128;
    const int z = blockIdx.z;
    const unsigned short* W = Wb + (size_t)z * 1048576;

    f32x4 acc[4][4];
#pragma unroll
    for (int i = 0; i < 4; ++i)
#pragma unroll
        for (int j = 0; j < 4; ++j) acc[i][j] = f32x4{0.f, 0.f, 0.f, 0.f};

    const int r = tid >> 2;
    const int c = (tid & 3) * 8;
    unsigned short* AsW = &As[wid * 512];
    unsigned short* BsW = &Bs[wid * 512];

    for (int k0 = 0; k0 < K; k0 += BK) {
        __syncthreads();
        if (A_BF16) {
            const unsigned short* A = (const unsigned short*)Av;
            async16(&A[(size_t)(m0 + r) * K + k0 + c], AsW);
            async16(&A[(size_t)(m0 + 64 + r) * K + k0 + c], AsW + 2048);
        } else {
            const float* A = (const float*)Av;
            stage8_f32(&As[tid * 8],        &A[(size_t)(m0 + r) * K + k0 + c]);
            stage8_f32(&As[tid * 8 + 2048], &A[(size_t)(m0 + 64 + r) * K + k0 + c]);
        }
        async16(&W[(size_t)(n0 + r) * K + k0 + c], BsW);
        async16(&W[(size_t)(n0 + 64 + r) * K + k0 + c], BsW + 2048);
        __syncthreads();

        bf16x8 af[4], bfr[4];
#pragma unroll
        for (int im = 0; im < 4; ++im) af[im]  = *(const bf16x8*)&As[(wm + im * 16 + l) * BK + g * 8];
#pragma unroll
        for (int in = 0; in < 4; ++in) bfr[in] = *(const bf16x8*)&Bs[(wn + in * 16 + l) * BK + g * 8];
#pragma unroll
        for (int im = 0; im < 4; ++im)
#pragma unroll
            for (int in = 0; in < 4; ++in)
                acc[im][in] = __builtin_amdgcn_mfma_f32_16x16x32_bf16(af[im], bfr[in], acc[im][in], 0, 0, 0);
    }

    unsigned short* outq = outv + (size_t)z * 4194304;
    if (z < 2) {
        float freq[2];
#pragma unroll
        for (int in = 0; in < 2; ++in)
            freq[in] = exp2f(-(float)(in * 16 + l) * 0.41524101186f);  // log2(10000)/32
#pragma unroll
        for (int im = 0; im < 4; ++im)
#pragma unroll
            for (int i = 0; i < 4; ++i) {
                const int m = m0 + wm + im * 16 + g * 4 + i;
                const int b = m >> 11, t = m & 2047;
#pragma unroll
                for (int in = 0; in < 2; ++in) {
                    const int n = n0 + wn + in * 16 + l;
                    const int h = n >> 6, d = n & 63;
                    const float ang = (float)t * freq[in];
                    const float cs = __cosf(ang), sn = __sinf(ang);
                    const float x1 = acc[im][in][i], x2 = acc[im][in + 2][i];
                    const size_t bidx = (((size_t)b * 16 + h) * 2048 + t) << 6;
                    outq[bidx + d]      = f2bf(x1 * cs - x2 * sn);
                    outq[bidx + d + 32] = f2bf(x2 * cs + x1 * sn);
                }
            }
    } else {
#pragma unroll
        for (int im = 0; im < 4; ++im)
#pragma unroll
            for (int in = 0; in < 4; ++in) {
                const int n = n0 + wn + in * 16 + l;
                const int h = n >> 6, d = n & 63;
#pragma unroll
                for (int i = 0; i < 4; ++i) {
                    const int m = m0 + wm + im * 16 + g * 4 + i;
                    const int b = m >> 11, t = m & 2047;
                    outq[((((size_t)b * 16 + h) * 2048 + t) << 6) + d] = f2bf(acc[im][in][i]);
                }
            }
    }
}

// Projection: C = A(bf16)[4096,1024] x Wo^T + bias, 64x128 tile -> 512 blocks (2/CU).
__global__ __launch_bounds__(256) void gemm_proj(
    const unsigned short* __restrict__ A, const unsigned short* __restrict__ W,
    float* __restrict__ out, const float* __restrict__ bias)
{
    constexpr int K = 1024, BK = 32;
    __shared__ __align__(16) unsigned short As[64 * BK];    // 4KB
    __shared__ __align__(16) unsigned short Bs[128 * BK];   // 8KB
    const int tid = threadIdx.x;
    const int wid = tid >> 6, lane = tid & 63, g = lane >> 4, l = lane & 15;
    const int wm = (wid & 1) * 32, wn = (wid >> 1) * 64;
    const int m0 = blockIdx.y * 64, n0 = blockIdx.x * 128;

    f32x4 acc[2][4];
#pragma unroll
    for (int i = 0; i < 2; ++i)
#pragma unroll
        for (int j = 0; j < 4; ++j) acc[i][j] = f32x4{0.f, 0.f, 0.f, 0.f};

    const int r = tid >> 2;
    const int c = (tid & 3) * 8;
    unsigned short* AsW = &As[wid * 512];
    unsigned short* BsW = &Bs[wid * 512];

    for (int k0 = 0; k0 < K; k0 += BK) {
        __syncthreads();
        async16(&A[(size_t)(m0 + r) * K + k0 + c], AsW);            // 64 rows (r<64 covers all)
        async16(&W[(size_t)(n0 + r) * K + k0 + c], BsW);
        async16(&W[(size_t)(n0 + 64 + r) * K + k0 + c], BsW + 2048);
        __syncthreads();

        bf16x8 af[2], bfr[4];
#pragma unroll
        for (int im = 0; im < 2; ++im) af[im]  = *(const bf16x8*)&As[(wm + im * 16 + l) * BK + g * 8];
#pragma unroll
        for (int in = 0; in < 4; ++in) bfr[in] = *(const bf16x8*)&Bs[(wn + in * 16 + l) * BK + g * 8];
#pragma unroll
        for (int im = 0; im < 2; ++im)
#pragma unroll
            for (int in = 0; in < 4; ++in)
                acc[im][in] = __builtin_amdgcn_mfma_f32_16x16x32_bf16(af[im], bfr[in], acc[im][in], 0, 0, 0);
    }

#pragma unroll
    for (int im = 0; im < 2; ++im)
#pragma unroll
        for (int in = 0; in < 4; ++in) {
            const int n = n0 + wn + in * 16 + l;
#pragma unroll
            for (int i = 0; i < 4; ++i) {
                const int m = m0 + wm + im * 16 + g * 4 + i;
                out[(size_t)m * 1024 + n] = acc[im][in][i] + bias[n];
            }
        }
}

// Flash attention, constant-max softmax (scores are O(1); fp32 exp exact-safe, no running max).
// 2048 blocks x 128 threads; block = (bh, 32-row q-tile), longest tiles first; 64-key chunks.
__global__ __launch_bounds__(128) void flash_attn(
    const unsigned short* __restrict__ QKV, const float* __restrict__ sbias,
    const float* __restrict__ sw, unsigned short* __restrict__ attn)
{
    constexpr int T = 2048;
    __shared__ __align__(16) unsigned short Ks[64 * 72];    // 9.2KB
    __shared__ __align__(16) unsigned short VsT[64 * 72];   // [d][key] 9.2KB
    __shared__ __align__(16) unsigned short Ps[2][16 * 72]; // 4.6KB
    const int tid = threadIdx.x, wid = tid >> 6, lane = tid & 63, g = lane >> 4, l = lane & 15;
    const int id = blockIdx.x;
    const int qt = 63 - (id >> 5);            // descending work: longest blocks dispatched first
    const int bh = id & 31, b = bh >> 4, h = bh & 15;

    const unsigned short* Q  = QKV;
    const unsigned short* Kg = QKV + 4194304;
    const unsigned short* Vg = QKV + 8388608;
    const size_t base = (size_t)bh * T * 64;
    const float bias = sbias[h];
    const float* swb = sw + b * T;

    bf16x8 onef;
#pragma unroll
    for (int q8 = 0; q8 < 8; ++q8) onef[q8] = (__bf16)1.0f;

    const int q0 = qt * 32;
    const int qrow = q0 + wid * 16 + l;
    const bf16x8 qf0 = *(const bf16x8*)&Q[base + (size_t)qrow * 64 + g * 8];
    const bf16x8 qf1 = *(const bf16x8*)&Q[base + (size_t)qrow * 64 + 32 + g * 8];

    float lrow[4] = {0.f, 0.f, 0.f, 0.f};
    f32x4 oacc[4];
#pragma unroll
    for (int dt = 0; dt < 4; ++dt) oacc[dt] = f32x4{0.f, 0.f, 0.f, 0.f};

    const int nchunk = (qt + 2) >> 1;         // keys needed: 32*qt+32
    for (int ch = 0; ch < nchunk; ++ch) {
        const int k0 = ch * 64;
        __syncthreads();
        {   // K: 64x64 bf16, 4 x 16B per thread (128 threads)
            const int kr = tid >> 3, kc = (tid & 7) * 8;
#pragma unroll
            for (int s = 0; s < 4; ++s)
                *(u16x8*)&Ks[(kr + s * 16) * 72 + kc] =
                    *(const u16x8*)&Kg[base + (size_t)(k0 + kr + s * 16) * 64 + kc];
        }
        {   // V transposed: thread loads key-pair (2r,2r+1) x 8 d (x2 halves), packs b32
            const int vr = (tid & 31) * 2;
#pragma unroll
            for (int s = 0; s < 2; ++s) {
                const int vd = (tid >> 5) * 8 + s * 32;
                const u16x8 v0 = *(const u16x8*)&Vg[base + (size_t)(k0 + vr) * 64 + vd];
                const u16x8 v1 = *(const u16x8*)&Vg[base + (size_t)(k0 + vr + 1) * 64 + vd];
#pragma unroll
                for (int jj = 0; jj < 8; ++jj) {
                    const unsigned int pack = (unsigned int)v0[jj] | ((unsigned int)v1[jj] << 16);
                    *(unsigned int*)&VsT[(vd + jj) * 72 + vr] = pack;
                }
            }
        }
        __syncthreads();

        // S = Q K^T; p = exp((s*SCALE + bias)*w)  -- no max subtraction needed
        const bool diag = (ch == nchunk - 1);
        float sv[4][4];
#pragma unroll
        for (int sub = 0; sub < 4; ++sub) {
            const bf16x8 kf0 = *(const bf16x8*)&Ks[(sub * 16 + l) * 72 + g * 8];
            const bf16x8 kf1 = *(const bf16x8*)&Ks[(sub * 16 + l) * 72 + 32 + g * 8];
            f32x4 s4 = f32x4{0.f, 0.f, 0.f, 0.f};
            s4 = __builtin_amdgcn_mfma_f32_16x16x32_bf16(qf0, kf0, s4, 0, 0, 0);
            s4 = __builtin_amdgcn_mfma_f32_16x16x32_bf16(qf1, kf1, s4, 0, 0, 0);
            const int kc = k0 + sub * 16 + l;
            const float w = swb[kc];
            const float a = w * 0.125f, cst = w * bias;
#pragma unroll
            for (int i = 0; i < 4; ++i) {
                float x = s4[i] * a + cst;
                if (diag) {
                    const int qr = q0 + wid * 16 + g * 4 + i;
                    x = (kc <= qr) ? x : -1e30f;      // exp -> 0
                }
                sv[sub][i] = __expf(x);
            }
        }

        // P: C-layout -> LDS -> A-layout (per-wave buffer, same-wave in-order)
#pragma unroll
        for (int sub = 0; sub < 4; ++sub)
#pragma unroll
            for (int i = 0; i < 4; ++i)
                Ps[wid][(g * 4 + i) * 72 + sub * 16 + l] = f2bf(sv[sub][i]);
        __threadfence_block();
        bf16x8 pf[2];
        pf[0] = *(const bf16x8*)&Ps[wid][l * 72 + g * 8];
        pf[1] = *(const bf16x8*)&Ps[wid][l * 72 + 32 + g * 8];

        // rowsum via ones-MFMA (C-layout rows match lrow)
        f32x4 ls = f32x4{0.f, 0.f, 0.f, 0.f};
        ls = __builtin_amdgcn_mfma_f32_16x16x32_bf16(pf[0], onef, ls, 0, 0, 0);
        ls = __builtin_amdgcn_mfma_f32_16x16x32_bf16(pf[1], onef, ls, 0, 0, 0);
#pragma unroll
        for (int i = 0; i < 4; ++i) lrow[i] += ls[i];

        // O += P V
#pragma unroll
        for (int ks = 0; ks < 2; ++ks)
#pragma unroll
            for (int dt = 0; dt < 4; ++dt) {
                const bf16x8 vf = *(const bf16x8*)&VsT[(dt * 16 + l) * 72 + ks * 32 + g * 8];
                oacc[dt] = __builtin_amdgcn_mfma_f32_16x16x32_bf16(pf[ks], vf, oacc[dt], 0, 0, 0);
            }
    }

#pragma unroll
    for (int i = 0; i < 4; ++i) lrow[i] = 1.0f / lrow[i];
#pragma unroll
    for (int dt = 0; dt < 4; ++dt)
#pragma unroll
        for (int i = 0; i < 4; ++i) {
            const int qr = q0 + wid * 16 + g * 4 + i;
            attn[(size_t)(b * T + qr) * 1024 + h * 64 + dt * 16 + l] = f2bf(oacc[dt][i] * lrow[i]);
        }
}

extern "C" void kernel_launch(void* const* d_in, const int* in_sizes, int n_in,
                              void* d_out, int out_size, void* d_ws, size_t ws_size,
                              hipStream_t stream) {
    const float* x  = (const float*)d_in[0];
    const float* Wq = (const float*)d_in[1];
    const float* Wk = (const float*)d_in[2];
    const float* Wv = (const float*)d_in[3];
    const float* Wo = (const float*)d_in[4];
    const float* bo = (const float*)d_in[5];
    const float* sb = (const float*)d_in[6];
    const float* sw = (const float*)d_in[7];

    const size_t QKV_SZ = 4194304;   // shorts per q/k/v tensor
    const size_t W_SZ   = 1048576;   // shorts per weight matrix
    unsigned short* ws16 = (unsigned short*)d_ws;
    const bool big = ws_size >= 2 * (4 * QKV_SZ + 4 * W_SZ);  // 41.9 MB

    if (big) {
        unsigned short* xb    = ws16;            // x bf16
        unsigned short* Wb3   = xb + QKV_SZ;     // Wq,Wk,Wv
        unsigned short* Wob   = Wb3 + 3 * W_SZ;  // Wo
        unsigned short* qkv   = Wob + W_SZ;      // q,k,v head-major
        unsigned short* attnb = xb;              // overlay x (dead after QKV gemm)

        cvt_all<<<4096, 256, 0, stream>>>(x, Wq, Wk, Wv, Wo, xb, 1, 1048576);
        gemm_qkv<1><<<dim3(8, 32, 3), 256, 0, stream>>>(xb, Wb3, qkv);
        flash_attn<<<2048, 128, 0, stream>>>(qkv, sb, sw, attnb);
        gemm_proj<<<dim3(8, 64), 256, 0, stream>>>(attnb, Wob, (float*)d_out, bo);
    } else {                                     // 33.6 MB fallback
        unsigned short* qkv   = ws16;
        unsigned short* attnb = qkv + 3 * QKV_SZ;
        unsigned short* Wb3   = attnb;           // overlay attn (dead until flash)
        unsigned short* Wob   = qkv;             // overlay q (dead after flash)

        cvt_all<<<1536, 256, 0, stream>>>(x, Wq, Wk, Wv, Wo, Wb3, 0, 393216);
        gemm_qkv<0><<<dim3(8, 32, 3), 256, 0, stream>>>(x, Wb3, qkv);
        flash_attn<<<2048, 128, 0, stream>>>(qkv, sb, sw, attnb);
        cvt_all<<<512, 256, 0, stream>>>(x, Wo, Wo, Wo, Wo, Wob, 0, 131072);
        gemm_proj<<<dim3(8, 64), 256, 0, stream>>>(attnb, Wob, (float*)d_out, bo);
    }
}

// Round 6
// 233.942 us; speedup vs baseline: 1.1000x; 1.1000x over previous
//
#include <hip/hip_runtime.h>

// QuantFinanceAttention: B=2, T=2048, C=1024, H=16, dk=64. fp32 I/O, bf16 MFMA internals.
// cvt(all) | QKV gemm (rope fused; V written pre-transposed [bh][d][t]) |
// flash (32x32x16 MFMA, 64q blocks, reg-prefetch staging, constant-max softmax) | proj.

typedef __bf16 bf16x8 __attribute__((ext_vector_type(8)));
typedef float f32x4 __attribute__((ext_vector_type(4)));
typedef float f32x16 __attribute__((ext_vector_type(16)));
typedef unsigned short u16x8 __attribute__((ext_vector_type(8)));

__device__ __forceinline__ unsigned short f2bf(float f) {
    union { float f; unsigned int u; } c; c.f = f;
    unsigned int u = c.u;
    unsigned int r = u + 0x7fffu + ((u >> 16) & 1u);  // RNE
    return (unsigned short)(r >> 16);
}
__device__ __forceinline__ void stage8_f32(unsigned short* dst, const float* src) {
    const float4 a = *(const float4*)src;
    const float4 b = *(const float4*)(src + 4);
    u16x8 v;
    v[0] = f2bf(a.x); v[1] = f2bf(a.y); v[2] = f2bf(a.z); v[3] = f2bf(a.w);
    v[4] = f2bf(b.x); v[5] = f2bf(b.y); v[6] = f2bf(b.z); v[7] = f2bf(b.w);
    *(u16x8*)dst = v;
}
__device__ __forceinline__ void async16(const unsigned short* g, unsigned short* l) {
    __builtin_amdgcn_global_load_lds(
        (const __attribute__((address_space(1))) void*)g,
        (__attribute__((address_space(3))) void*)l, 16, 0, 0);
}

// Fused fp32->bf16 convert. dst layout: [x(524288 g8) if hasX][Wq][Wk][Wv][Wo] (131072 g8 each).
__global__ __launch_bounds__(256) void cvt_all(
    const float* __restrict__ x, const float* __restrict__ Wq, const float* __restrict__ Wk,
    const float* __restrict__ Wv, const float* __restrict__ Wo,
    unsigned short* __restrict__ dst, int hasX, int n8)
{
    const int i = blockIdx.x * 256 + threadIdx.x;
    if (i >= n8) return;
    int r = i;
    const float* src; int off;
    const int xg = hasX ? 524288 : 0;
    if (r < xg) { src = x; off = r; }
    else {
        r -= xg;
        const int w = r >> 17, o = r & 131071;
        src = (w == 0) ? Wq : (w == 1) ? Wk : (w == 2) ? Wv : Wo;
        off = o;
    }
    stage8_f32(&dst[(size_t)i * 8], &src[(size_t)off * 8]);
}

// QKV: C[m,n] = sum_k A[m,k]*W[n,k], K=1024, 128x128 tile. W bf16 at base + z*1M.
// z<2 (Q,K): rope fused, out [z][bh][t][d]. z==2 (V): out transposed [bh][d][t] (b64 packs).
template<int A_BF16>
__global__ __launch_bounds__(256) void gemm_qkv(
    const void* __restrict__ Av, const unsigned short* __restrict__ Wb,
    unsigned short* __restrict__ outv)
{
    constexpr int K = 1024, BK = 32;
    __shared__ __align__(16) unsigned short As[128 * BK];
    __shared__ __align__(16) unsigned short Bs[128 * BK];
    const int tid = threadIdx.x;
    const int wid = tid >> 6, lane = tid & 63, g = lane >> 4, l = lane & 15;
    const int wm = (wid & 1) * 64, wn = (wid >> 1) * 64;
    const int m0 = blockIdx.y * 128, n0 = blockIdx.x * 128;
    const int z = blockIdx.z;
    const unsigned short* W = Wb + (size_t)z * 1048576;

    f32x4 acc[4][4];
#pragma unroll
    for (int i = 0; i < 4; ++i)
#pragma unroll
        for (int j = 0; j < 4; ++j) acc[i][j] = f32x4{0.f, 0.f, 0.f, 0.f};

    const int r = tid >> 2;
    const int c = (tid & 3) * 8;
    unsigned short* AsW = &As[wid * 512];
    unsigned short* BsW = &Bs[wid * 512];

    for (int k0 = 0; k0 < K; k0 += BK) {
        __syncthreads();
        if (A_BF16) {
            const unsigned short* A = (const unsigned short*)Av;
            async16(&A[(size_t)(m0 + r) * K + k0 + c], AsW);
            async16(&A[(size_t)(m0 + 64 + r) * K + k0 + c], AsW + 2048);
        } else {
            const float* A = (const float*)Av;
            stage8_f32(&As[tid * 8],        &A[(size_t)(m0 + r) * K + k0 + c]);
            stage8_f32(&As[tid * 8 + 2048], &A[(size_t)(m0 + 64 + r) * K + k0 + c]);
        }
        async16(&W[(size_t)(n0 + r) * K + k0 + c], BsW);
        async16(&W[(size_t)(n0 + 64 + r) * K + k0 + c], BsW + 2048);
        __syncthreads();

        bf16x8 af[4], bfr[4];
#pragma unroll
        for (int im = 0; im < 4; ++im) af[im]  = *(const bf16x8*)&As[(wm + im * 16 + l) * BK + g * 8];
#pragma unroll
        for (int in = 0; in < 4; ++in) bfr[in] = *(const bf16x8*)&Bs[(wn + in * 16 + l) * BK + g * 8];
#pragma unroll
        for (int im = 0; im < 4; ++im)
#pragma unroll
            for (int in = 0; in < 4; ++in)
                acc[im][in] = __builtin_amdgcn_mfma_f32_16x16x32_bf16(af[im], bfr[in], acc[im][in], 0, 0, 0);
    }

    unsigned short* outq = outv + (size_t)z * 4194304;
    if (z < 2) {
        float freq[2];
#pragma unroll
        for (int in = 0; in < 2; ++in)
            freq[in] = exp2f(-(float)(in * 16 + l) * 0.41524101186f);  // log2(10000)/32
#pragma unroll
        for (int im = 0; im < 4; ++im)
#pragma unroll
            for (int i = 0; i < 4; ++i) {
                const int m = m0 + wm + im * 16 + g * 4 + i;
                const int b = m >> 11, t = m & 2047;
#pragma unroll
                for (int in = 0; in < 2; ++in) {
                    const int n = n0 + wn + in * 16 + l;
                    const int h = n >> 6, d = n & 63;
                    const float ang = (float)t * freq[in];
                    const float cs = __cosf(ang), sn = __sinf(ang);
                    const float x1 = acc[im][in][i], x2 = acc[im][in + 2][i];
                    const size_t bidx = (((size_t)b * 16 + h) * 2048 + t) << 6;
                    outq[bidx + d]      = f2bf(x1 * cs - x2 * sn);
                    outq[bidx + d + 32] = f2bf(x2 * cs + x1 * sn);
                }
            }
    } else {
        // V transposed: [bh][d][t], 4 consecutive t per C-reg quad -> b64 stores
#pragma unroll
        for (int im = 0; im < 4; ++im)
#pragma unroll
            for (int in = 0; in < 4; ++in) {
                const int n = n0 + wn + in * 16 + l;
                const int h = n >> 6, d = n & 63;
                const int mb = m0 + wm + im * 16 + g * 4;
                const int bq = mb >> 11, t0 = mb & 2047;
                ushort4 pk;
                pk.x = f2bf(acc[im][in][0]); pk.y = f2bf(acc[im][in][1]);
                pk.z = f2bf(acc[im][in][2]); pk.w = f2bf(acc[im][in][3]);
                *(ushort4*)&outq[((size_t)(bq * 16 + h)) * 131072 + (size_t)d * 2048 + t0] = pk;
            }
    }
}

// Projection: C = A(bf16)[4096,1024] x Wo^T + bias, 64x128 tile -> 512 blocks (2/CU).
__global__ __launch_bounds__(256) void gemm_proj(
    const unsigned short* __restrict__ A, const unsigned short* __restrict__ W,
    float* __restrict__ out, const float* __restrict__ bias)
{
    constexpr int K = 1024, BK = 32;
    __shared__ __align__(16) unsigned short As[64 * BK];
    __shared__ __align__(16) unsigned short Bs[128 * BK];
    const int tid = threadIdx.x;
    const int wid = tid >> 6, lane = tid & 63, g = lane >> 4, l = lane & 15;
    const int wm = (wid & 1) * 32, wn = (wid >> 1) * 64;
    const int m0 = blockIdx.y * 64, n0 = blockIdx.x * 128;

    f32x4 acc[2][4];
#pragma unroll
    for (int i = 0; i < 2; ++i)
#pragma unroll
        for (int j = 0; j < 4; ++j) acc[i][j] = f32x4{0.f, 0.f, 0.f, 0.f};

    const int r = tid >> 2;
    const int c = (tid & 3) * 8;
    unsigned short* AsW = &As[wid * 512];
    unsigned short* BsW = &Bs[wid * 512];

    for (int k0 = 0; k0 < K; k0 += BK) {
        __syncthreads();
        async16(&A[(size_t)(m0 + r) * K + k0 + c], AsW);
        async16(&W[(size_t)(n0 + r) * K + k0 + c], BsW);
        async16(&W[(size_t)(n0 + 64 + r) * K + k0 + c], BsW + 2048);
        __syncthreads();

        bf16x8 af[2], bfr[4];
#pragma unroll
        for (int im = 0; im < 2; ++im) af[im]  = *(const bf16x8*)&As[(wm + im * 16 + l) * BK + g * 8];
#pragma unroll
        for (int in = 0; in < 4; ++in) bfr[in] = *(const bf16x8*)&Bs[(wn + in * 16 + l) * BK + g * 8];
#pragma unroll
        for (int im = 0; im < 2; ++im)
#pragma unroll
            for (int in = 0; in < 4; ++in)
                acc[im][in] = __builtin_amdgcn_mfma_f32_16x16x32_bf16(af[im], bfr[in], acc[im][in], 0, 0, 0);
    }

#pragma unroll
    for (int im = 0; im < 2; ++im)
#pragma unroll
        for (int in = 0; in < 4; ++in) {
            const int n = n0 + wn + in * 16 + l;
#pragma unroll
            for (int i = 0; i < 4; ++i) {
                const int m = m0 + wm + im * 16 + g * 4 + i;
                out[(size_t)m * 1024 + n] = acc[im][in][i] + bias[n];
            }
        }
}

// Flash attention, 32x32x16 MFMA. Block = 128 threads (2 waves x 32 q-rows = 64-q tile).
// 64-key chunks; K and V^T staged via register prefetch (loads overlap compute).
// Constant-max softmax (scores O(1), fp32 exp exact-safe). 1024 blocks, longest-first.
__global__ __launch_bounds__(128) void flash_attn(
    const unsigned short* __restrict__ Q, const unsigned short* __restrict__ Kg,
    const unsigned short* __restrict__ VT, const float* __restrict__ sbias,
    const float* __restrict__ sw, unsigned short* __restrict__ attn)
{
    constexpr int T = 2048;
    __shared__ __align__(16) unsigned short Ks[64 * 72];     // [key][d]
    __shared__ __align__(16) unsigned short VsT[64 * 72];    // [d][key]
    __shared__ __align__(16) unsigned short Ps[2][32 * 72];  // per-wave P [q][key]
    const int tid = threadIdx.x, wid = tid >> 6, lane = tid & 63;
    const int hl = lane & 31, hh = lane >> 5;
    const int id = blockIdx.x;
    const int qt = 31 - (id >> 5);                 // longest tiles dispatched first
    const int bh = id & 31, b = bh >> 4, h = bh & 15;
    const size_t base = (size_t)bh * T * 64;       // Q/K: [t][d]
    const size_t vtb  = (size_t)bh * 64 * T;       // V^T: [d][t]
    const float bias = sbias[h];
    const float* swb = sw + b * T;

    bf16x8 onef;
#pragma unroll
    for (int j = 0; j < 8; ++j) onef[j] = (__bf16)1.0f;

    const int q0 = qt * 64;
    const int qrow = q0 + wid * 32 + hl;           // A-operand row (m = hl)
    bf16x8 qf[4];
#pragma unroll
    for (int ks = 0; ks < 4; ++ks)
        qf[ks] = *(const bf16x8*)&Q[base + (size_t)qrow * 64 + ks * 16 + hh * 8];

    f32x16 oacc[2], lrow;
#pragma unroll
    for (int r = 0; r < 16; ++r) { oacc[0][r] = 0.f; oacc[1][r] = 0.f; lrow[r] = 0.f; }

    // prefetch chunk 0 into registers
    u16x8 kpre[4], vpre[4];
#pragma unroll
    for (int s = 0; s < 4; ++s) {
        const int ci = s * 128 + tid, rr = ci >> 3, c8 = (ci & 7) * 8;
        kpre[s] = *(const u16x8*)&Kg[base + (size_t)rr * 64 + c8];
        vpre[s] = *(const u16x8*)&VT[vtb + (size_t)rr * T + c8];
    }

    const int nch = qt + 1;
    for (int ch = 0; ch < nch; ++ch) {
        const int k0 = ch * 64;
        __syncthreads();
#pragma unroll
        for (int s = 0; s < 4; ++s) {              // regs -> LDS
            const int ci = s * 128 + tid, rr = ci >> 3, c8 = (ci & 7) * 8;
            *(u16x8*)&Ks[rr * 72 + c8]  = kpre[s];
            *(u16x8*)&VsT[rr * 72 + c8] = vpre[s];
        }
        __syncthreads();
        if (ch + 1 < nch) {                        // issue next-chunk loads; overlap compute
            const int k1 = k0 + 64;
#pragma unroll
            for (int s = 0; s < 4; ++s) {
                const int ci = s * 128 + tid, rr = ci >> 3, c8 = (ci & 7) * 8;
                kpre[s] = *(const u16x8*)&Kg[base + (size_t)(k1 + rr) * 64 + c8];
                vpre[s] = *(const u16x8*)&VT[vtb + (size_t)rr * T + k1 + c8];
            }
        }

        // S = Q K^T : 2 n-tiles (32 keys each) x 4 k-steps
        f32x16 sx[2];
#pragma unroll
        for (int r = 0; r < 16; ++r) { sx[0][r] = 0.f; sx[1][r] = 0.f; }
#pragma unroll
        for (int ks = 0; ks < 4; ++ks)
#pragma unroll
            for (int nt = 0; nt < 2; ++nt) {
                const bf16x8 kf = *(const bf16x8*)&Ks[(nt * 32 + hl) * 72 + ks * 16 + hh * 8];
                sx[nt] = __builtin_amdgcn_mfma_f32_32x32x16_bf16(qf[ks], kf, sx[nt], 0, 0, 0);
            }

        // p = exp((s*SCALE + bias)*w) with causal mask on diag chunk; write P to LDS
        const bool diag = (ch == nch - 1);
        const float w0 = swb[k0 + hl], w1 = swb[k0 + 32 + hl];
#pragma unroll
        for (int nt = 0; nt < 2; ++nt) {
            const float w = nt ? w1 : w0;
            const float a = w * 0.125f, cst = w * bias;
            const int kc = k0 + nt * 32 + hl;
#pragma unroll
            for (int r = 0; r < 16; ++r) {
                const int row = (r & 3) + 8 * (r >> 2) + 4 * hh;
                float xv = sx[nt][r] * a + cst;
                if (diag) {
                    const int qr = q0 + wid * 32 + row;
                    xv = (kc <= qr) ? xv : -1e30f;  // exp -> 0
                }
                Ps[wid][row * 72 + nt * 32 + hl] = f2bf(__expf(xv));
            }
        }
        __threadfence_block();
        bf16x8 pf[4];                              // A-layout: [m=q=hl][k=key]
#pragma unroll
        for (int ks = 0; ks < 4; ++ks)
            pf[ks] = *(const bf16x8*)&Ps[wid][hl * 72 + ks * 16 + hh * 8];

        // rowsum via ones-MFMA (C rows match oacc rows)
        f32x16 ls;
#pragma unroll
        for (int r = 0; r < 16; ++r) ls[r] = 0.f;
#pragma unroll
        for (int ks = 0; ks < 4; ++ks)
            ls = __builtin_amdgcn_mfma_f32_32x32x16_bf16(pf[ks], onef, ls, 0, 0, 0);
#pragma unroll
        for (int r = 0; r < 16; ++r) lrow[r] += ls[r];

        // O += P V : B-frag = V^T[d][key]
#pragma unroll
        for (int ks = 0; ks < 4; ++ks)
#pragma unroll
            for (int dt = 0; dt < 2; ++dt) {
                const bf16x8 vf = *(const bf16x8*)&VsT[(dt * 32 + hl) * 72 + ks * 16 + hh * 8];
                oacc[dt] = __builtin_amdgcn_mfma_f32_32x32x16_bf16(pf[ks], vf, oacc[dt], 0, 0, 0);
            }
    }

#pragma unroll
    for (int r = 0; r < 16; ++r) lrow[r] = 1.0f / lrow[r];
#pragma unroll
    for (int dt = 0; dt < 2; ++dt)
#pragma unroll
        for (int r = 0; r < 16; ++r) {
            const int row = (r & 3) + 8 * (r >> 2) + 4 * hh;
            const int qr = q0 + wid * 32 + row;
            attn[(size_t)(b * T + qr) * 1024 + h * 64 + dt * 32 + hl] = f2bf(oacc[dt][r] * lrow[r]);
        }
}

extern "C" void kernel_launch(void* const* d_in, const int* in_sizes, int n_in,
                              void* d_out, int out_size, void* d_ws, size_t ws_size,
                              hipStream_t stream) {
    const float* x  = (const float*)d_in[0];
    const float* Wq = (const float*)d_in[1];
    const float* Wk = (const float*)d_in[2];
    const float* Wv = (const float*)d_in[3];
    const float* Wo = (const float*)d_in[4];
    const float* bo = (const float*)d_in[5];
    const float* sb = (const float*)d_in[6];
    const float* sw = (const float*)d_in[7];

    const size_t QKV_SZ = 4194304;   // shorts per q/k/v tensor
    const size_t W_SZ   = 1048576;   // shorts per weight matrix
    unsigned short* ws16 = (unsigned short*)d_ws;
    const bool big = ws_size >= 2 * (4 * QKV_SZ + 4 * W_SZ);  // 41.9 MB

    if (big) {
        unsigned short* xb    = ws16;            // x bf16
        unsigned short* Wb3   = xb + QKV_SZ;     // Wq,Wk,Wv
        unsigned short* Wob   = Wb3 + 3 * W_SZ;  // Wo
        unsigned short* qkv   = Wob + W_SZ;      // q,k (head-major), v^T
        unsigned short* attnb = xb;              // overlay x (dead after QKV gemm)

        cvt_all<<<4096, 256, 0, stream>>>(x, Wq, Wk, Wv, Wo, xb, 1, 1048576);
        gemm_qkv<1><<<dim3(8, 32, 3), 256, 0, stream>>>(xb, Wb3, qkv);
        flash_attn<<<1024, 128, 0, stream>>>(qkv, qkv + QKV_SZ, qkv + 2 * QKV_SZ,
                                             sb, sw, attnb);
        gemm_proj<<<dim3(8, 64), 256, 0, stream>>>(attnb, Wob, (float*)d_out, bo);
    } else {                                     // 33.6 MB fallback
        unsigned short* qkv   = ws16;
        unsigned short* attnb = qkv + 3 * QKV_SZ;
        unsigned short* Wb3   = attnb;           // overlay attn (dead until flash)
        unsigned short* Wob   = qkv;             // overlay q (dead after flash)

        cvt_all<<<1536, 256, 0, stream>>>(x, Wq, Wk, Wv, Wo, Wb3, 0, 393216);
        gemm_qkv<0><<<dim3(8, 32, 3), 256, 0, stream>>>(x, Wb3, qkv);
        flash_attn<<<1024, 128, 0, stream>>>(qkv, qkv + QKV_SZ, qkv + 2 * QKV_SZ,
                                             sb, sw, attnb);
        cvt_all<<<512, 256, 0, stream>>>(x, Wo, Wo, Wo, Wo, Wob, 0, 131072);
        gemm_proj<<<dim3(8, 64), 256, 0, stream>>>(attnb, Wob, (float*)d_out, bo);
    }
}